// Round 2
// baseline (2241.496 us; speedup 1.0000x reference)
//
#include <hip/hip_runtime.h>
#include <math.h>

#define NROWS 65536
#define DIM 256
#define KC 1024

// ---------------------------------------------------------------------------
// Kernel 1: row norms for inputs (xn) and embeddings (en); zero loss accum;
// init packed argmin array to u64-max. One 64-lane wave per row.
// Deterministic shuffle-tree sum (xn feeds the argmin scores; error profile
// must stay close to numpy pairwise summation).
// ---------------------------------------------------------------------------
__global__ void __launch_bounds__(256) vq_norms(const float* __restrict__ x,
                                                const float* __restrict__ e,
                                                float* __restrict__ xn,
                                                float* __restrict__ en,
                                                unsigned long long* __restrict__ packed,
                                                float* __restrict__ accum) {
    if (blockIdx.x == 0 && threadIdx.x == 0) *accum = 0.0f;
    const int wave = threadIdx.x >> 6;
    const int lane = threadIdx.x & 63;
    const int row = blockIdx.x * 4 + wave;   // grid sized exactly (NROWS+KC)/4
    const float* src;
    float* dst;
    if (row < NROWS) {
        src = x + (size_t)row * DIM;
        dst = xn + row;
        if (lane == 0) packed[row] = ~0ull;   // atomicMin identity
    } else {
        int er = row - NROWS;                 // always < KC by grid sizing
        src = e + (size_t)er * DIM;
        dst = en + er;
    }
    float4 v = ((const float4*)src)[lane];
    float s = (v.x * v.x + v.y * v.y) + (v.z * v.z + v.w * v.w);
#pragma unroll
    for (int off = 1; off < 64; off <<= 1)
        s += __shfl_xor(s, off, 64);
    if (lane == 0) *dst = s;
}

// ---------------------------------------------------------------------------
// Kernel 2: fused distance-GEMM + row argmin, split over the code dim.
// Grid = (rows/128) x (codes/128) = 512 x 8 = 4096 blocks -> 16 blocks/CU
// queued, 4 resident (LDS 36.9KB, VGPR<=128 via launch_bounds(256,4)).
// Tile layout [row][d] with +4 pad: float4 staging writes, ds_read_b128
// fragment reads. Per-thread 8x8 microtile; d-accumulation order identical
// to R1 (matches np argmin decisions). Cross-block merge via atomicMin on
// packed (float_bits(dist)<<32)|code -- dist>0 so float bit order is
// monotone; low word gives np first-occurrence tie-break.
// ---------------------------------------------------------------------------
__global__ void __launch_bounds__(256, 4) vq_argmin(const float* __restrict__ X,
                                                    const float* __restrict__ E,
                                                    const float* __restrict__ xn,
                                                    const float* __restrict__ en,
                                                    unsigned long long* __restrict__ packed) {
    __shared__ float Xs[128][36];   // +4 pad: keeps float4 alignment, rotates banks
    __shared__ float Es[128][36];

    const int tid = threadIdx.x;
    const int tx = tid & 15;
    const int ty = tid >> 4;
    const size_t rowBase = (size_t)blockIdx.x * 128;
    const size_t codeBase = (size_t)blockIdx.y * 128;

    const int sr = tid >> 3;         // staging row-in-tile 0..31
    const int sc = (tid & 7) * 4;    // staging col (float4 granule)

    float dot[8][8];
#pragma unroll
    for (int i = 0; i < 8; i++)
#pragma unroll
        for (int j = 0; j < 8; j++) dot[i][j] = 0.0f;

    float xnr[8];
#pragma unroll
    for (int i = 0; i < 8; i++) xnr[i] = xn[rowBase + ty + i * 16];

    for (int dk = 0; dk < DIM; dk += 32) {
        __syncthreads();
#pragma unroll
        for (int g = 0; g < 4; g++) {
            int r = sr + g * 32;
            float4 vx = *(const float4*)(X + (rowBase + r) * (size_t)DIM + dk + sc);
            *(float4*)&Xs[r][sc] = vx;
            float4 ve = *(const float4*)(E + (codeBase + r) * (size_t)DIM + dk + sc);
            *(float4*)&Es[r][sc] = ve;
        }
        __syncthreads();
#pragma unroll
        for (int g4 = 0; g4 < 8; g4++) {
#pragma unroll
            for (int h = 0; h < 2; h++) {   // 4-row halves keep VGPR <= 128
                float4 a0 = *(const float4*)&Xs[ty + (4 * h + 0) * 16][g4 * 4];
                float4 a1 = *(const float4*)&Xs[ty + (4 * h + 1) * 16][g4 * 4];
                float4 a2 = *(const float4*)&Xs[ty + (4 * h + 2) * 16][g4 * 4];
                float4 a3 = *(const float4*)&Xs[ty + (4 * h + 3) * 16][g4 * 4];
#pragma unroll
                for (int j = 0; j < 8; j++) {
                    float4 b4 = *(const float4*)&Es[tx + j * 16][g4 * 4];
                    float d0 = dot[4 * h + 0][j];
                    float d1 = dot[4 * h + 1][j];
                    float d2 = dot[4 * h + 2][j];
                    float d3 = dot[4 * h + 3][j];
                    d0 = fmaf(a0.x, b4.x, d0); d0 = fmaf(a0.y, b4.y, d0);
                    d0 = fmaf(a0.z, b4.z, d0); d0 = fmaf(a0.w, b4.w, d0);
                    d1 = fmaf(a1.x, b4.x, d1); d1 = fmaf(a1.y, b4.y, d1);
                    d1 = fmaf(a1.z, b4.z, d1); d1 = fmaf(a1.w, b4.w, d1);
                    d2 = fmaf(a2.x, b4.x, d2); d2 = fmaf(a2.y, b4.y, d2);
                    d2 = fmaf(a2.z, b4.z, d2); d2 = fmaf(a2.w, b4.w, d2);
                    d3 = fmaf(a3.x, b4.x, d3); d3 = fmaf(a3.y, b4.y, d3);
                    d3 = fmaf(a3.z, b4.z, d3); d3 = fmaf(a3.w, b4.w, d3);
                    dot[4 * h + 0][j] = d0;
                    dot[4 * h + 1][j] = d1;
                    dot[4 * h + 2][j] = d2;
                    dot[4 * h + 3][j] = d3;
                }
            }
        }
    }

    // scores + per-thread packed argmin over this block's 8 code columns
    unsigned long long best[8];
#pragma unroll
    for (int i = 0; i < 8; i++) best[i] = ~0ull;
#pragma unroll
    for (int j = 0; j < 8; j++) {
        int code = (int)codeBase + tx + j * 16;
        float enc = en[code];
#pragma unroll
        for (int i = 0; i < 8; i++) {
            float s = fmaf(-2.0f, dot[i][j], xnr[i] + enc);
            unsigned long long p =
                ((unsigned long long)__float_as_uint(s) << 32) | (unsigned int)code;
            if (p < best[i]) best[i] = p;
        }
    }

    // cross-thread (over tx) reduction per row, reusing Xs as u64 scratch
    __syncthreads();
    unsigned long long* red = (unsigned long long*)&Xs[0][0];  // 128*17*8 = 17408 <= 18432
#pragma unroll
    for (int i = 0; i < 8; i++) red[(ty + i * 16) * 17 + tx] = best[i];
    __syncthreads();
    if (tid < 128) {
        unsigned long long b = red[tid * 17];
#pragma unroll
        for (int t = 1; t < 16; t++) {
            unsigned long long v = red[tid * 17 + t];
            if (v < b) b = v;
        }
        atomicMin(&packed[rowBase + tid], b);
    }
}

// ---------------------------------------------------------------------------
// Kernel 3: gather quantized rows + fused squared-diff partial sums.
// One wave per row (float4 per lane), 16 rows per block.
// ---------------------------------------------------------------------------
__global__ void __launch_bounds__(256) vq_gather(const float* __restrict__ X,
                                                 const float* __restrict__ E,
                                                 const unsigned long long* __restrict__ packed,
                                                 float* __restrict__ out,
                                                 float* __restrict__ accum) {
    const int tid = threadIdx.x;
    const int wave = tid >> 6;
    const int lane = tid & 63;
    const size_t rowBase = (size_t)blockIdx.x * 16;
    float part = 0.0f;
#pragma unroll
    for (int rr = 0; rr < 4; rr++) {
        size_t row = rowBase + wave + rr * 4;
        int code = (int)(unsigned int)(packed[row] & 0xffffffffull);
        float4 q = ((const float4*)(E + (size_t)code * DIM))[lane];
        float4 xv = ((const float4*)(X + row * DIM))[lane];
        ((float4*)(out + row * DIM))[lane] = q;
        float dx = q.x - xv.x, dy = q.y - xv.y, dz = q.z - xv.z, dw = q.w - xv.w;
        part = fmaf(dx, dx, part);
        part = fmaf(dy, dy, part);
        part = fmaf(dz, dz, part);
        part = fmaf(dw, dw, part);
    }
#pragma unroll
    for (int off = 1; off < 64; off <<= 1)
        part += __shfl_xor(part, off, 64);
    __shared__ float red[4];
    if ((tid & 63) == 0) red[tid >> 6] = part;
    __syncthreads();
    if (tid == 0) {
        float s = (red[0] + red[1]) + (red[2] + red[3]);
        atomicAdd(accum, s);
    }
}

// ---------------------------------------------------------------------------
// Kernel 4: finalize scalar loss. mean = sum / 2^24 (exact divide),
// vq_loss = q_latent + e_latent = 2*mean (exact add).
// ---------------------------------------------------------------------------
__global__ void vq_finalize(const float* __restrict__ accum,
                            float* __restrict__ loss) {
    float m = *accum * (1.0f / 16777216.0f);
    *loss = m + m;
}

extern "C" void kernel_launch(void* const* d_in, const int* in_sizes, int n_in,
                              void* d_out, int out_size, void* d_ws, size_t ws_size,
                              hipStream_t stream) {
    const float* X = (const float*)d_in[0];   // [65536, 256]
    const float* E = (const float*)d_in[1];   // [1024, 256]
    float* out = (float*)d_out;               // [65536*256] quantized + [1] loss

    char* ws = (char*)d_ws;
    float* xn = (float*)ws;                                         // 65536 f32
    float* en = (float*)(ws + 262144);                              // 1024 f32
    unsigned long long* packed = (unsigned long long*)(ws + 266240); // 65536 u64
    float* accum = (float*)(ws + 266240 + 524288);                  // 1 f32

    vq_norms  <<<(NROWS + KC) / 4, 256, 0, stream>>>(X, E, xn, en, packed, accum);
    vq_argmin <<<dim3(NROWS / 128, KC / 128), 256, 0, stream>>>(X, E, xn, en, packed);
    vq_gather <<<NROWS / 16, 256, 0, stream>>>(X, E, packed, out, accum);
    vq_finalize<<<1, 1, 0, stream>>>(accum, out + (size_t)NROWS * DIM);
}

// Round 3
// 598.137 us; speedup vs baseline: 3.7475x; 3.7475x over previous
//
#include <hip/hip_runtime.h>
#include <math.h>

#define NROWS 65536
#define DIM 256
#define KC 1024

// ---------------------------------------------------------------------------
// Kernel 1: row norms for inputs (xn) and embeddings (en); zero loss accum;
// init packed argmin array to u64-max. One 64-lane wave per row.
// ---------------------------------------------------------------------------
__global__ void __launch_bounds__(256) vq_norms(const float* __restrict__ x,
                                                const float* __restrict__ e,
                                                float* __restrict__ xn,
                                                float* __restrict__ en,
                                                unsigned long long* __restrict__ packed,
                                                float* __restrict__ accum) {
    if (blockIdx.x == 0 && threadIdx.x == 0) *accum = 0.0f;
    const int wave = threadIdx.x >> 6;
    const int lane = threadIdx.x & 63;
    const int row = blockIdx.x * 4 + wave;   // grid sized exactly (NROWS+KC)/4
    const float* src;
    float* dst;
    if (row < NROWS) {
        src = x + (size_t)row * DIM;
        dst = xn + row;
        if (lane == 0) packed[row] = ~0ull;   // atomicMin identity
    } else {
        int er = row - NROWS;                 // always < KC by grid sizing
        src = e + (size_t)er * DIM;
        dst = en + er;
    }
    float4 v = ((const float4*)src)[lane];
    float s = (v.x * v.x + v.y * v.y) + (v.z * v.z + v.w * v.w);
#pragma unroll
    for (int off = 1; off < 64; off <<= 1)
        s += __shfl_xor(s, off, 64);
    if (lane == 0) *dst = s;
}

// ---------------------------------------------------------------------------
// Kernel 2: fused distance-GEMM + row argmin, split over the code dim.
// Grid = (rows/128) x (codes/128) = 4096 blocks. NO occupancy-forcing
// launch_bounds: R2 showed (256,4) caps VGPR at 64 -> dot[8][8] spills to
// scratch -> 6 GB of HBM spill traffic. Plain (256) compiles to ~128 VGPR
// (R1-verified), 4 blocks/CU resident (LDS 36.9 KB).
// Tile layout [row][d] +4 pad: float4 staging writes, ds_read_b128 reads.
// d-accumulation order identical to R1 (matches np argmin decisions).
// Cross-block merge via atomicMin on (float_bits(dist)<<32)|code.
// ---------------------------------------------------------------------------
__global__ void __launch_bounds__(256) vq_argmin(const float* __restrict__ X,
                                                 const float* __restrict__ E,
                                                 const float* __restrict__ xn,
                                                 const float* __restrict__ en,
                                                 unsigned long long* __restrict__ packed) {
    __shared__ float Xs[128][36];   // stride 36 floats: b128-phase-uniform banks
    __shared__ float Es[128][36];

    const int tid = threadIdx.x;
    const int tx = tid & 15;
    const int ty = tid >> 4;
    const size_t rowBase = (size_t)blockIdx.x * 128;
    const size_t codeBase = (size_t)blockIdx.y * 128;

    const int sr = tid >> 3;         // staging row-in-tile 0..31
    const int sc = (tid & 7) * 4;    // staging col (float4 granule)

    float dot[8][8];
#pragma unroll
    for (int i = 0; i < 8; i++)
#pragma unroll
        for (int j = 0; j < 8; j++) dot[i][j] = 0.0f;

    float xnr[8];
#pragma unroll
    for (int i = 0; i < 8; i++) xnr[i] = xn[rowBase + ty + i * 16];

    for (int dk = 0; dk < DIM; dk += 32) {
        __syncthreads();
#pragma unroll
        for (int g = 0; g < 4; g++) {
            int r = sr + g * 32;
            float4 vx = *(const float4*)(X + (rowBase + r) * (size_t)DIM + dk + sc);
            *(float4*)&Xs[r][sc] = vx;
            float4 ve = *(const float4*)(E + (codeBase + r) * (size_t)DIM + dk + sc);
            *(float4*)&Es[r][sc] = ve;
        }
        __syncthreads();
#pragma unroll
        for (int g4 = 0; g4 < 8; g4++) {
#pragma unroll
            for (int h = 0; h < 2; h++) {   // 4-row halves keep live set ~100 VGPR
                float4 a0 = *(const float4*)&Xs[ty + (4 * h + 0) * 16][g4 * 4];
                float4 a1 = *(const float4*)&Xs[ty + (4 * h + 1) * 16][g4 * 4];
                float4 a2 = *(const float4*)&Xs[ty + (4 * h + 2) * 16][g4 * 4];
                float4 a3 = *(const float4*)&Xs[ty + (4 * h + 3) * 16][g4 * 4];
#pragma unroll
                for (int j = 0; j < 8; j++) {
                    float4 b4 = *(const float4*)&Es[tx + j * 16][g4 * 4];
                    float d0 = dot[4 * h + 0][j];
                    float d1 = dot[4 * h + 1][j];
                    float d2 = dot[4 * h + 2][j];
                    float d3 = dot[4 * h + 3][j];
                    d0 = fmaf(a0.x, b4.x, d0); d0 = fmaf(a0.y, b4.y, d0);
                    d0 = fmaf(a0.z, b4.z, d0); d0 = fmaf(a0.w, b4.w, d0);
                    d1 = fmaf(a1.x, b4.x, d1); d1 = fmaf(a1.y, b4.y, d1);
                    d1 = fmaf(a1.z, b4.z, d1); d1 = fmaf(a1.w, b4.w, d1);
                    d2 = fmaf(a2.x, b4.x, d2); d2 = fmaf(a2.y, b4.y, d2);
                    d2 = fmaf(a2.z, b4.z, d2); d2 = fmaf(a2.w, b4.w, d2);
                    d3 = fmaf(a3.x, b4.x, d3); d3 = fmaf(a3.y, b4.y, d3);
                    d3 = fmaf(a3.z, b4.z, d3); d3 = fmaf(a3.w, b4.w, d3);
                    dot[4 * h + 0][j] = d0;
                    dot[4 * h + 1][j] = d1;
                    dot[4 * h + 2][j] = d2;
                    dot[4 * h + 3][j] = d3;
                }
            }
        }
    }

    // scores + per-thread packed argmin over this block's 8 code columns
    unsigned long long best[8];
#pragma unroll
    for (int i = 0; i < 8; i++) best[i] = ~0ull;
#pragma unroll
    for (int j = 0; j < 8; j++) {
        int code = (int)codeBase + tx + j * 16;
        float enc = en[code];
#pragma unroll
        for (int i = 0; i < 8; i++) {
            float s = fmaf(-2.0f, dot[i][j], xnr[i] + enc);
            unsigned long long p =
                ((unsigned long long)__float_as_uint(s) << 32) | (unsigned int)code;
            if (p < best[i]) best[i] = p;
        }
    }

    // cross-thread (over tx) reduction per row, reusing Xs as u64 scratch
    __syncthreads();
    unsigned long long* red = (unsigned long long*)&Xs[0][0];  // 128*17*8 = 17408 <= 18432
#pragma unroll
    for (int i = 0; i < 8; i++) red[(ty + i * 16) * 17 + tx] = best[i];
    __syncthreads();
    if (tid < 128) {
        unsigned long long b = red[tid * 17];
#pragma unroll
        for (int t = 1; t < 16; t++) {
            unsigned long long v = red[tid * 17 + t];
            if (v < b) b = v;
        }
        atomicMin(&packed[rowBase + tid], b);
    }
}

// ---------------------------------------------------------------------------
// Kernel 3: gather quantized rows + fused squared-diff partial sums.
// One wave per row (float4 per lane), 16 rows per block.
// ---------------------------------------------------------------------------
__global__ void __launch_bounds__(256) vq_gather(const float* __restrict__ X,
                                                 const float* __restrict__ E,
                                                 const unsigned long long* __restrict__ packed,
                                                 float* __restrict__ out,
                                                 float* __restrict__ accum) {
    const int tid = threadIdx.x;
    const int wave = tid >> 6;
    const int lane = tid & 63;
    const size_t rowBase = (size_t)blockIdx.x * 16;
    float part = 0.0f;
#pragma unroll
    for (int rr = 0; rr < 4; rr++) {
        size_t row = rowBase + wave + rr * 4;
        int code = (int)(unsigned int)(packed[row] & 0xffffffffull);
        float4 q = ((const float4*)(E + (size_t)code * DIM))[lane];
        float4 xv = ((const float4*)(X + row * DIM))[lane];
        ((float4*)(out + row * DIM))[lane] = q;
        float dx = q.x - xv.x, dy = q.y - xv.y, dz = q.z - xv.z, dw = q.w - xv.w;
        part = fmaf(dx, dx, part);
        part = fmaf(dy, dy, part);
        part = fmaf(dz, dz, part);
        part = fmaf(dw, dw, part);
    }
#pragma unroll
    for (int off = 1; off < 64; off <<= 1)
        part += __shfl_xor(part, off, 64);
    __shared__ float red[4];
    if ((tid & 63) == 0) red[tid >> 6] = part;
    __syncthreads();
    if (tid == 0) {
        float s = (red[0] + red[1]) + (red[2] + red[3]);
        atomicAdd(accum, s);
    }
}

// ---------------------------------------------------------------------------
// Kernel 4: finalize scalar loss. mean = sum / 2^24 (exact divide),
// vq_loss = q_latent + e_latent = 2*mean (exact add).
// ---------------------------------------------------------------------------
__global__ void vq_finalize(const float* __restrict__ accum,
                            float* __restrict__ loss) {
    float m = *accum * (1.0f / 16777216.0f);
    *loss = m + m;
}

extern "C" void kernel_launch(void* const* d_in, const int* in_sizes, int n_in,
                              void* d_out, int out_size, void* d_ws, size_t ws_size,
                              hipStream_t stream) {
    const float* X = (const float*)d_in[0];   // [65536, 256]
    const float* E = (const float*)d_in[1];   // [1024, 256]
    float* out = (float*)d_out;               // [65536*256] quantized + [1] loss

    char* ws = (char*)d_ws;
    float* xn = (float*)ws;                                          // 65536 f32
    float* en = (float*)(ws + 262144);                               // 1024 f32
    unsigned long long* packed = (unsigned long long*)(ws + 266240); // 65536 u64
    float* accum = (float*)(ws + 266240 + 524288);                   // 1 f32

    vq_norms  <<<(NROWS + KC) / 4, 256, 0, stream>>>(X, E, xn, en, packed, accum);
    vq_argmin <<<dim3(NROWS / 128, KC / 128), 256, 0, stream>>>(X, E, xn, en, packed);
    vq_gather <<<NROWS / 16, 256, 0, stream>>>(X, E, packed, out, accum);
    vq_finalize<<<1, 1, 0, stream>>>(accum, out + (size_t)NROWS * DIM);
}